// Round 21
// baseline (160.690 us; speedup 1.0000x reference)
//
#include <hip/hip_runtime.h>
#include <hip/hip_bf16.h>
#include <stdint.h>

#define DEV __device__ __forceinline__

typedef __attribute__((ext_vector_type(4))) float f32x4;
typedef __attribute__((ext_vector_type(8))) __bf16 bf16x8;
typedef __attribute__((ext_vector_type(4))) __bf16 bf16x4;
typedef __attribute__((ext_vector_type(4))) unsigned int uint4v;
typedef __attribute__((ext_vector_type(4))) int i32x4;

static constexpr int Bc = 4, Sc = 1024, DMc = 1024, Hc = 16, Dh = 64;
static constexpr int Mc = Bc * Sc; // 4096

DEV __bf16 f2b(float x) {
    unsigned u = __builtin_bit_cast(unsigned, x);
    unsigned r = (u + 0x7fffu + ((u >> 16) & 1u)) >> 16;
    return __builtin_bit_cast(__bf16, (unsigned short)r);
}
DEV float b2f(__bf16 x) {
    unsigned short s = __builtin_bit_cast(unsigned short, x);
    unsigned u = ((unsigned)s) << 16;
    return __builtin_bit_cast(float, u);
}
DEV unsigned cvt_pk_bf16(float a, float b) {
    unsigned r;
    asm("v_cvt_pk_bf16_f32 %0, %1, %2" : "=v"(r) : "v"(a), "v"(b));
    return r;
}
DEV void gload_lds16(const void* g, void* l) {
    __builtin_amdgcn_global_load_lds(
        (const __attribute__((address_space(1))) unsigned int*)g,
        (__attribute__((address_space(3))) unsigned int*)l,
        16, 0, 0);
}
// BK=64 swizzled LDS read: tile row-major [row][64 bf16] (128B rows), col-unit cu in [0,8)
DEV bf16x8 ldswz(const __bf16* base, int row, int cu) {
    const char* p = (const char*)base + row * 128 + (((cu) ^ (row & 7)) << 4);
    return *(const bf16x8*)p;
}

// ======= unified prep: z<5 -> weight transpose-convert; z==5 -> hs cvt + col partials ==
__global__ void k_prep(const float* __restrict__ s0, const float* __restrict__ s1,
                       const float* __restrict__ s2, const float* __restrict__ s3,
                       const float* __restrict__ s4,
                       __bf16* __restrict__ d0, __bf16* __restrict__ d1,
                       __bf16* __restrict__ d2, __bf16* __restrict__ d3,
                       __bf16* __restrict__ d4, __bf16* __restrict__ wqb,
                       const float* __restrict__ hs, __bf16* __restrict__ hsb,
                       float* __restrict__ part0) {
    const int tid = threadIdx.x;
    if (blockIdx.z == 5) {
        int idx = blockIdx.y * 32 + blockIdx.x;
        if (idx >= 512) return;
        int sc = idx >> 2, b = idx & 3;
        int c0 = tid * 4;
        float4 s = {0.f, 0.f, 0.f, 0.f};
#pragma unroll
        for (int r = 0; r < 8; r++) {
            size_t row = (size_t)b * 1024 + sc * 8 + r;
            float4 v = *(const float4*)&hs[row * 1024 + c0];
            s.x += v.x; s.y += v.y; s.z += v.z; s.w += v.w;
            bf16x4 o = { f2b(v.x), f2b(v.y), f2b(v.z), f2b(v.w) };
            *(bf16x4*)&hsb[row * 1024 + c0] = o;
        }
        *(float4*)&part0[(size_t)(sc * 4 + b) * 1024 + c0] = s;
        return;
    }
    __shared__ float t[32][33];
    const float* in; __bf16* out;
    switch (blockIdx.z) {
        case 0: in = s0; out = d0; break;
        case 1: in = s1; out = d1; break;
        case 2: in = s2; out = d2; break;
        case 3: in = s3; out = d3; break;
        default: in = s4; out = d4; break;
    }
    int tx = tid & 31, ty = tid >> 5;
    int c0 = blockIdx.x * 32, r0 = blockIdx.y * 32;
    for (int j = 0; j < 4; j++) {
        float v = in[(size_t)(r0 + ty + j * 8) * 1024 + c0 + tx];
        t[ty + j * 8][tx] = v;
        if (blockIdx.z == 0)
            wqb[(size_t)(r0 + ty + j * 8) * 1024 + c0 + tx] = f2b(v);
    }
    __syncthreads();
    for (int j = 0; j < 4; j++)
        out[(size_t)(c0 + ty + j * 8) * 1024 + r0 + tx] = f2b(t[tx][ty + j * 8]);
}

// ------- generic GEMM, BK=64, dbuf min-2-phase pipeline, swizzled LDS (R8 proven) -----
template <int EPI, int BM>
__global__ __launch_bounds__(256) void k_gemm(
    const __bf16* __restrict__ A, const __bf16* __restrict__ Bt,
    const float* __restrict__ bias, void* __restrict__ Cout, int N, int K)
{
    constexpr int MF = BM / 32;
    constexpr int ACH = BM / 32;
    __shared__ __bf16 Al[2][BM * 64];
    __shared__ __bf16 Bl[2][128 * 64];
    const int bm = blockIdx.x, bn = blockIdx.y;
    const int tid = threadIdx.x, lane = tid & 63, wid = tid >> 6;
    const int l15 = lane & 15, lg = lane >> 4;
    const int qr = (wid >> 1) * (BM / 2), qc = (wid & 1) * 64;
    f32x4 acc[MF][4] = {};

    const __bf16* Ab = A + (size_t)bm * BM * K;
    const __bf16* Bb = Bt + (size_t)bn * 128 * K;

#pragma unroll
    for (int c = 0; c < ACH; c++) {
        int ch = c * 256 + tid, row = ch >> 3, cu = (ch & 7) ^ (row & 7);
        gload_lds16(&Ab[(size_t)row * K + cu * 8], &Al[0][ch * 8]);
    }
#pragma unroll
    for (int c = 0; c < 4; c++) {
        int ch = c * 256 + tid, row = ch >> 3, cu = (ch & 7) ^ (row & 7);
        gload_lds16(&Bb[(size_t)row * K + cu * 8], &Bl[0][ch * 8]);
    }
    asm volatile("s_waitcnt vmcnt(0)" ::: "memory");
    __builtin_amdgcn_s_barrier();

    int buf = 0;
    for (int t = 0; t < K / 64; t++) {
        if (t + 1 < K / 64) {
            int k0 = (t + 1) * 64;
#pragma unroll
            for (int c = 0; c < ACH; c++) {
                int ch = c * 256 + tid, row = ch >> 3, cu = (ch & 7) ^ (row & 7);
                gload_lds16(&Ab[(size_t)row * K + k0 + cu * 8], &Al[buf ^ 1][ch * 8]);
            }
#pragma unroll
            for (int c = 0; c < 4; c++) {
                int ch = c * 256 + tid, row = ch >> 3, cu = (ch & 7) ^ (row & 7);
                gload_lds16(&Bb[(size_t)row * K + k0 + cu * 8], &Bl[buf ^ 1][ch * 8]);
            }
        }
        bf16x8 af[MF][2], bfv[4][2];
#pragma unroll
        for (int m = 0; m < MF; m++)
#pragma unroll
            for (int ks = 0; ks < 2; ks++) af[m][ks] = ldswz(&Al[buf][0], qr + m * 16 + l15, ks * 4 + lg);
#pragma unroll
        for (int n = 0; n < 4; n++)
#pragma unroll
            for (int ks = 0; ks < 2; ks++) bfv[n][ks] = ldswz(&Bl[buf][0], qc + n * 16 + l15, ks * 4 + lg);
#pragma unroll
        for (int m = 0; m < MF; m++)
#pragma unroll
            for (int n = 0; n < 4; n++) {
                acc[m][n] = __builtin_amdgcn_mfma_f32_16x16x32_bf16(af[m][0], bfv[n][0], acc[m][n], 0, 0, 0);
                acc[m][n] = __builtin_amdgcn_mfma_f32_16x16x32_bf16(af[m][1], bfv[n][1], acc[m][n], 0, 0, 0);
            }
        asm volatile("s_waitcnt vmcnt(0)" ::: "memory");
        __builtin_amdgcn_s_barrier();
        buf ^= 1;
    }
#pragma unroll
    for (int m = 0; m < MF; m++) {
        int row_base = bm * BM + qr + m * 16 + lg * 4;
#pragma unroll
        for (int n = 0; n < 4; n++) {
            int col = bn * 128 + qc + n * 16 + l15;
            float bsum = bias ? bias[col] : 0.0f;
#pragma unroll
            for (int r = 0; r < 4; r++) {
                int row = row_base + r;
                float v = acc[m][n][r] + bsum;
                if constexpr (EPI == 2) ((float*)Cout)[(size_t)row * N + col] = v;
                else ((__bf16*)Cout)[(size_t)row * N + col] = f2b(v);
            }
        }
    }
}

// ======= fused QKV+C GEMM, 128x128, BK=64 dbuf, fused P/Z + fused V-transpose (R8) ====
__global__ __launch_bounds__(256) void k_qkvc(
    const __bf16* __restrict__ A, const __bf16* __restrict__ BtAll,
    const float* __restrict__ bq, const float* __restrict__ bk, const float* __restrict__ bv,
    const float* __restrict__ gt2, const float* __restrict__ up, const float* __restrict__ uz,
    __bf16* __restrict__ mq, __bf16* __restrict__ mk_, __bf16* __restrict__ vt,
    float* __restrict__ Pf, float* __restrict__ Zf)
{
    constexpr int K = 1024;
    __shared__ __bf16 Al[2][128 * 64];
    __shared__ __bf16 Bl[2][128 * 64];
    const int bm = blockIdx.x, bn = blockIdx.y;
    const int tid = threadIdx.x, lane = tid & 63, wid = tid >> 6;
    const int l15 = lane & 15, lg = lane >> 4;
    const int qr = (wid >> 1) * 64, qc = (wid & 1) * 64;
    f32x4 acc[4][4] = {};

    const __bf16* Ab = A + (size_t)bm * 128 * K;
    const __bf16* Bb = BtAll + (size_t)bn * 128 * K;

#pragma unroll
    for (int c = 0; c < 4; c++) {
        int ch = c * 256 + tid, row = ch >> 3, cu = (ch & 7) ^ (row & 7);
        gload_lds16(&Ab[(size_t)row * K + cu * 8], &Al[0][ch * 8]);
        gload_lds16(&Bb[(size_t)row * K + cu * 8], &Bl[0][ch * 8]);
    }
    asm volatile("s_waitcnt vmcnt(0)" ::: "memory");
    __builtin_amdgcn_s_barrier();

    int buf = 0;
    for (int t = 0; t < 16; t++) {
        if (t < 15) {
            int k0 = (t + 1) * 64;
#pragma unroll
            for (int c = 0; c < 4; c++) {
                int ch = c * 256 + tid, row = ch >> 3, cu = (ch & 7) ^ (row & 7);
                gload_lds16(&Ab[(size_t)row * K + k0 + cu * 8], &Al[buf ^ 1][ch * 8]);
                gload_lds16(&Bb[(size_t)row * K + k0 + cu * 8], &Bl[buf ^ 1][ch * 8]);
            }
        }
        bf16x8 af[4][2], bfv[4][2];
#pragma unroll
        for (int m = 0; m < 4; m++)
#pragma unroll
            for (int ks = 0; ks < 2; ks++) af[m][ks] = ldswz(&Al[buf][0], qr + m * 16 + l15, ks * 4 + lg);
#pragma unroll
        for (int n = 0; n < 4; n++)
#pragma unroll
            for (int ks = 0; ks < 2; ks++) bfv[n][ks] = ldswz(&Bl[buf][0], qc + n * 16 + l15, ks * 4 + lg);
#pragma unroll
        for (int m = 0; m < 4; m++)
#pragma unroll
            for (int n = 0; n < 4; n++) {
                acc[m][n] = __builtin_amdgcn_mfma_f32_16x16x32_bf16(af[m][0], bfv[n][0], acc[m][n], 0, 0, 0);
                acc[m][n] = __builtin_amdgcn_mfma_f32_16x16x32_bf16(af[m][1], bfv[n][1], acc[m][n], 0, 0, 0);
            }
        asm volatile("s_waitcnt vmcnt(0)" ::: "memory");
        __builtin_amdgcn_s_barrier();
        buf ^= 1;
    }

    const int chunk = bn >> 3;
    if (chunk == 3) {
        const int h = (bn & 7) * 2 + (qc >> 6);
        float upv[4], uzv[4];
#pragma unroll
        for (int n = 0; n < 4; n++) {
            upv[n] = up[h * 64 + n * 16 + l15];
            uzv[n] = uz[h * 64 + n * 16 + l15];
        }
#pragma unroll
        for (int m = 0; m < 4; m++) {
            int row_base = bm * 128 + qr + m * 16 + lg * 4;
#pragma unroll
            for (int r = 0; r < 4; r++) {
                int row = row_base + r;
                float p = 0.f, z = 0.f;
#pragma unroll
                for (int n = 0; n < 4; n++) {
                    int col = (bn & 7) * 128 + qc + n * 16 + l15;
                    float cv = tanhf(acc[m][n][r] + gt2[(row >> 10) * 1024 + col]);
                    p += cv * upv[n];
                    z += cv * uzv[n];
                }
#pragma unroll
                for (int d = 1; d < 16; d <<= 1) {
                    p += __shfl_xor(p, d, 16);
                    z += __shfl_xor(z, d, 16);
                }
                if (l15 == 0) {
                    int bb = row >> 10, s = row & 1023;
                    Pf[((size_t)(bb * 16 + h)) * 1024 + s] = 1024.f / (1.f + __expf(-p));
                    Zf[((size_t)(bb * 16 + h)) * 1024 + s] = 1024.f / (1.f + __expf(-z));
                }
            }
        }
    } else if (chunk == 2) {
        const int b = bm >> 3;
#pragma unroll
        for (int m = 0; m < 4; m++) {
            int s0 = (bm & 7) * 128 + qr + m * 16 + lg * 4;
#pragma unroll
            for (int n = 0; n < 4; n++) {
                int col = (bn & 7) * 128 + qc + n * 16 + l15;
                int h = col >> 6, d = col & 63;
                float bsum = bv[col];
                bf16x4 o = { f2b(acc[m][n][0] + bsum), f2b(acc[m][n][1] + bsum),
                             f2b(acc[m][n][2] + bsum), f2b(acc[m][n][3] + bsum) };
                *(bf16x4*)&vt[((size_t)((b * 16 + h) * 64 + d)) * 1024 + s0] = o;
            }
        }
    } else {
        const float* bias = chunk == 0 ? bq : bk;
        __bf16* outp = chunk == 0 ? mq : mk_;
#pragma unroll
        for (int m = 0; m < 4; m++) {
            int row_base = bm * 128 + qr + m * 16 + lg * 4;
#pragma unroll
            for (int n = 0; n < 4; n++) {
                int col = (bn & 7) * 128 + qc + n * 16 + l15;
                float bsum = bias[col];
#pragma unroll
                for (int r = 0; r < 4; r++) {
                    int row = row_base + r;
                    outp[(size_t)row * 1024 + col] = f2b(acc[m][n][r] + bsum);
                }
            }
        }
    }
}

// ---------------- focus-path small kernels (fp32, deterministic reductions) ------------
__global__ void k_glo2(const float* __restrict__ part0, const float* __restrict__ wq,
                       float* __restrict__ glo_part) {
    __shared__ float ghs_l[256];
    int tid = threadIdx.x, kc = blockIdx.y;
    {
        int bb = tid >> 6, kk = tid & 63, k = kc * 64 + kk;
        float s = 0.f;
        for (int sc = 0; sc < 128; sc++) s += part0[(size_t)(sc * 4 + bb) * 1024 + k];
        ghs_l[tid] = s * (1.0f / 1024.f);
    }
    __syncthreads();
    int n = blockIdx.x * 256 + tid;
    float a0 = 0, a1 = 0, a2 = 0, a3 = 0;
    for (int j = 0; j < 64; j++) {
        float w = wq[(size_t)(kc * 64 + j) * 1024 + n];
        a0 += ghs_l[j] * w; a1 += ghs_l[64 + j] * w; a2 += ghs_l[128 + j] * w; a3 += ghs_l[192 + j] * w;
    }
    glo_part[(kc * 4 + 0) * 1024 + n] = a0;
    glo_part[(kc * 4 + 1) * 1024 + n] = a1;
    glo_part[(kc * 4 + 2) * 1024 + n] = a2;
    glo_part[(kc * 4 + 3) * 1024 + n] = a3;
}
__global__ void k_gt2p(const float* __restrict__ glo_part, const float* __restrict__ bq,
                       const float* __restrict__ wfg, const float* __restrict__ wfq,
                       float* __restrict__ gt_part) {
    __shared__ float glo_l[256];
    int tid = threadIdx.x, kc = blockIdx.y;
    {
        int bb = tid >> 6, kk = tid & 63, k = kc * 64 + kk;
        float s = bq[k];
        for (int k2 = 0; k2 < 16; k2++) s += glo_part[(k2 * 4 + bb) * 1024 + k];
        glo_l[tid] = s;
    }
    __syncthreads();
    int n = blockIdx.x * 256 + tid;
    float a0 = 0, a1 = 0, a2 = 0, a3 = 0, t = 0;
    for (int j = 0; j < 64; j++) {
        int k = kc * 64 + j;
        float wg = wfg[(size_t)k * 1024 + n];
        float wf = wfq[(size_t)k * 1024 + n];
        a0 += glo_l[j] * wg; a1 += glo_l[64 + j] * wg; a2 += glo_l[128 + j] * wg; a3 += glo_l[192 + j] * wg;
        t += bq[k] * wf;
    }
    gt_part[(kc * 4 + 0) * 1024 + n] = a0 + t;
    gt_part[(kc * 4 + 1) * 1024 + n] = a1 + t;
    gt_part[(kc * 4 + 2) * 1024 + n] = a2 + t;
    gt_part[(kc * 4 + 3) * 1024 + n] = a3 + t;
}
__global__ void k_red_gt(const float* __restrict__ gt_part, const float* __restrict__ bfg,
                         const float* __restrict__ bfq, float* __restrict__ gt2) {
    int i = blockIdx.x * 256 + threadIdx.x;
    int b = i >> 10, n = i & 1023;
    float s = bfg[n] + bfq[n];
    for (int kc = 0; kc < 16; kc++) s += gt_part[(kc * 4 + b) * 1024 + n];
    gt2[i] = s;
}

// ---- flash attention, QBLK=64 (4 blocks/CU), swapped-QK^T, no-max softmax, deferred l -
DEV bf16x8 ldfrag(const __bf16* base, int row, int colbyte) {
    const char* p = (const char*)base + (size_t)row * 128 + (colbyte ^ ((row & 7) << 4));
    return *(const bf16x8*)p;
}

__global__ __launch_bounds__(256) void k_attn(
    const __bf16* __restrict__ Q, const __bf16* __restrict__ Kx, const __bf16* __restrict__ Vt_g,
    const float* __restrict__ Pf, const float* __restrict__ Zf, __bf16* __restrict__ ctx)
{
    __shared__ __bf16 Kl[2][64 * 64];
    __shared__ __bf16 Vl[2][64 * 64];
    const int qt = blockIdx.x, h = blockIdx.y, b = blockIdx.z;
    const int tid = threadIdx.x, lane = tid & 63, wid = tid >> 6;
    const int l15 = lane & 15, lg = lane >> 4;
    const int qbase = qt * 64 + wid * 16;      // 16 q-rows per wave
    const size_t qoff = ((size_t)(b * Sc)) * DMc + h * Dh;

    bf16x8 qf[2];
#pragma unroll
    for (int dh = 0; dh < 2; dh++)
        qf[dh] = *(const bf16x8*)&Q[qoff + (size_t)(qbase + l15) * DMc + dh * 32 + lg * 8];

    float Pr, Ar;
    {
        int row = qbase + l15;
        Pr = Pf[((size_t)(b * 16 + h)) * 1024 + row];
        float zz = Zf[((size_t)(b * 16 + h)) * 1024 + row];
        Ar = 2.0f / (zz * zz);
    }
    float l = 0.f;   // lane-local partial; cross-lane reduced once in epilogue
    f32x4 oacc[4] = {};

    const __bf16* Kbase = Kx + qoff;
    const __bf16* Vbase = Vt_g + ((size_t)((b * 16 + h) * 64)) * 1024;

#pragma unroll
    for (int i = 0; i < 2; i++) {
        int ch = i * 256 + tid, row = ch >> 3, off = ch & 7;
        uint4v kv = *(const uint4v*)&Kbase[(size_t)row * DMc + off * 8];
        uint4v vv = *(const uint4v*)&Vbase[(size_t)row * 1024 + off * 8];
        *(uint4v*)((char*)&Kl[0][0] + row * 128 + ((off * 16) ^ ((row & 7) << 4))) = kv;
        *(uint4v*)((char*)&Vl[0][0] + row * 128 + ((off * 16) ^ ((row & 7) << 4))) = vv;
    }
    __syncthreads();

    for (int t = 0; t < 16; t++) {
        const int buf = t & 1;
        uint4v rk[2], rv[2];
        if (t < 15) {
#pragma unroll
            for (int i = 0; i < 2; i++) {
                int ch = i * 256 + tid, row = ch >> 3, off = ch & 7;
                rk[i] = *(const uint4v*)&Kbase[(size_t)((t + 1) * 64 + row) * DMc + off * 8];
                rv[i] = *(const uint4v*)&Vbase[(size_t)row * 1024 + (t + 1) * 64 + off * 8];
            }
        }

        f32x4 st[4];
        __builtin_amdgcn_s_setprio(1);
#pragma unroll
        for (int c = 0; c < 4; c++) {
            bf16x8 kb0 = ldfrag(&Kl[buf][0], c * 16 + l15, lg * 16);
            bf16x8 kb1 = ldfrag(&Kl[buf][0], c * 16 + l15, 64 + lg * 16);
            f32x4 a = {0.f, 0.f, 0.f, 0.f};
            a = __builtin_amdgcn_mfma_f32_16x16x32_bf16(kb0, qf[0], a, 0, 0, 0);
            a = __builtin_amdgcn_mfma_f32_16x16x32_bf16(kb1, qf[1], a, 0, 0, 0);
            st[c] = a;
        }
        __builtin_amdgcn_s_setprio(0);

        // no-max softmax; l accumulation is linear so the cross-lane reduce is DEFERRED
        int pk[4][2];
        {
            float s[16];
            float base = (float)(t * 64 + lg * 4) - Pr;
#pragma unroll
            for (int c = 0; c < 4; c++)
#pragma unroll
                for (int r = 0; r < 4; r++) {
                    float dk = base + (float)(c * 16 + r);
                    s[c * 4 + r] = __expf(st[c][r] * 0.125f - dk * dk * Ar);
                }
            float rs = 0.f;
#pragma unroll
            for (int i = 0; i < 16; i++) rs += s[i];
            l += rs;
#pragma unroll
            for (int c = 0; c < 4; c++) {
                pk[c][0] = (int)cvt_pk_bf16(s[c * 4 + 0], s[c * 4 + 1]);
                pk[c][1] = (int)cvt_pk_bf16(s[c * 4 + 2], s[c * 4 + 3]);
            }
        }

        const int a0 = (((lg & 1) << 1) * 16 + l15) * 4;
        const int a1 = a0 + 64;
        const int selhi = lg >> 1;
#pragma unroll
        for (int kh = 0; kh < 2; kh++) {
            bf16x8 vb[4];
#pragma unroll
            for (int dt = 0; dt < 4; dt++) vb[dt] = ldfrag(&Vl[buf][0], dt * 16 + l15, kh * 64 + lg * 16);
            int w[4];
#pragma unroll
            for (int wi = 0; wi < 4; wi++) {
                int addr = (wi < 2) ? a0 : a1;
                int pr = wi & 1;
                int va = __builtin_amdgcn_ds_bpermute(addr, pk[kh * 2 + 0][pr]);
                int vb2 = __builtin_amdgcn_ds_bpermute(addr, pk[kh * 2 + 1][pr]);
                w[wi] = selhi ? vb2 : va;
            }
            i32x4 wv = {w[0], w[1], w[2], w[3]};
            bf16x8 pa = __builtin_bit_cast(bf16x8, wv);
            __builtin_amdgcn_s_setprio(1);
#pragma unroll
            for (int dt = 0; dt < 4; dt++)
                oacc[dt] = __builtin_amdgcn_mfma_f32_16x16x32_bf16(pa, vb[dt], oacc[dt], 0, 0, 0);
            __builtin_amdgcn_s_setprio(0);
        }

        if (t < 15) {
#pragma unroll
            for (int i = 0; i < 2; i++) {
                int ch = i * 256 + tid, row = ch >> 3, off = ch & 7;
                *(uint4v*)((char*)&Kl[buf ^ 1][0] + row * 128 + ((off * 16) ^ ((row & 7) << 4))) = rk[i];
                *(uint4v*)((char*)&Vl[buf ^ 1][0] + row * 128 + ((off * 16) ^ ((row & 7) << 4))) = rv[i];
            }
        }
        __syncthreads();
    }

    // epilogue: single cross-lane reduce of l, then normalize (rcp) + store
    l += __shfl_xor(l, 16, 64);
    l += __shfl_xor(l, 32, 64);
    float lr[4];
#pragma unroll
    for (int r = 0; r < 4; r++) lr[r] = __builtin_amdgcn_rcpf(__shfl(l, lg * 4 + r, 16));
#pragma unroll
    for (int dt = 0; dt < 4; dt++)
#pragma unroll
        for (int r = 0; r < 4; r++) {
            int row = qbase + lg * 4 + r;
            ctx[((size_t)(b * Sc) + row) * DMc + h * Dh + dt * 16 + l15] =
                f2b(oacc[dt][r] * lr[r]);
        }
}

extern "C" void kernel_launch(void* const* d_in, const int* in_sizes, int n_in,
                              void* d_out, int out_size, void* d_ws, size_t ws_size,
                              hipStream_t stream) {
    const float* hs  = (const float*)d_in[0];
    const float* wq  = (const float*)d_in[1];
    const float* bq  = (const float*)d_in[2];
    const float* wk  = (const float*)d_in[3];
    const float* bk  = (const float*)d_in[4];
    const float* wv  = (const float*)d_in[5];
    const float* bv  = (const float*)d_in[6];
    const float* wo  = (const float*)d_in[7];
    const float* bo  = (const float*)d_in[8];
    const float* wfq = (const float*)d_in[9];
    const float* bfq = (const float*)d_in[10];
    const float* wfg = (const float*)d_in[11];
    const float* bfg = (const float*)d_in[12];
    const float* up  = (const float*)d_in[13];
    const float* uz  = (const float*)d_in[14];

    char* ws = (char*)d_ws;
    const size_t MB = 1ull << 20;
    __bf16* hsb   = (__bf16*)(ws);            // 8MB (reused by ctxb after qkvc)
    __bf16* BtAll = (__bf16*)(ws + 8 * MB);   // 8MB: [wqT|wkT|wvT|wqfT] as [4096][1024]
    __bf16* wfqT  = (__bf16*)(ws + 16 * MB);  // 2MB
    __bf16* woT   = (__bf16*)(ws + 18 * MB);  // 2MB
    __bf16* mq    = (__bf16*)(ws + 20 * MB);
    __bf16* mk    = (__bf16*)(ws + 28 * MB);
    __bf16* vt    = (__bf16*)(ws + 36 * MB);
    __bf16* ctxb  = (__bf16*)(ws);
    __bf16* wqb   = (__bf16*)(ws + 55 * MB);  // 2MB: wq row-major bf16
    char* sm = ws + 52 * MB;
    float* Pf       = (float*)(sm);                   // 256KB
    float* Zf       = (float*)(sm + (256 << 10));     // 256KB
    float* glo_part = (float*)(sm + (512 << 10));     // 256KB
    float* gt_part  = (float*)(sm + (768 << 10));     // 256KB
    float* gt2      = (float*)(sm + (1024 << 10));    // 16KB
    float* part0    = (float*)(ws + 57 * MB);         // 2MB

    k_prep<<<dim3(32, 32, 6), 256, 0, stream>>>(
        wq, wk, wv, wfq, wo,
        BtAll, BtAll + 1048576, BtAll + 2097152, wfqT, woT, wqb,
        hs, hsb, part0);

    k_glo2<<<dim3(4, 16), 256, 0, stream>>>(part0, wq, glo_part);
    k_gt2p<<<dim3(4, 16), 256, 0, stream>>>(glo_part, bq, wfg, wfq, gt_part);
    k_red_gt<<<16, 256, 0, stream>>>(gt_part, bfg, bfq, gt2);

    // BtAll slice 3 <- wqf^T where wqf = wq@wfq  (A = wfqT, Bt = wq row-major)
    k_gemm<0, 32><<<dim3(32, 8), 256, 0, stream>>>(wfqT, wqb, nullptr, BtAll + 3145728, DMc, DMc);

    // fused QKV + focus-c GEMM with in-epilogue P/Z and V-transpose
    k_qkvc<<<dim3(32, 32), 256, 0, stream>>>(hsb, BtAll, bq, bk, bv, gt2, up, uz,
                                             mq, mk, vt, Pf, Zf);

    k_attn<<<dim3(16, 16, 4), 256, 0, stream>>>(mq, mk, vt, Pf, Zf, ctxb);

    k_gemm<2, 64><<<dim3(64, 8), 256, 0, stream>>>(ctxb, woT, bo, d_out, DMc, DMc);
}

// Round 22
// 159.481 us; speedup vs baseline: 1.0076x; 1.0076x over previous
//
#include <hip/hip_runtime.h>
#include <hip/hip_bf16.h>
#include <stdint.h>

#define DEV __device__ __forceinline__

typedef __attribute__((ext_vector_type(4))) float f32x4;
typedef __attribute__((ext_vector_type(8))) __bf16 bf16x8;
typedef __attribute__((ext_vector_type(4))) __bf16 bf16x4;
typedef __attribute__((ext_vector_type(4))) unsigned int uint4v;
typedef __attribute__((ext_vector_type(4))) int i32x4;

static constexpr int Bc = 4, Sc = 1024, DMc = 1024, Hc = 16, Dh = 64;
static constexpr int Mc = Bc * Sc; // 4096

DEV __bf16 f2b(float x) {
    unsigned u = __builtin_bit_cast(unsigned, x);
    unsigned r = (u + 0x7fffu + ((u >> 16) & 1u)) >> 16;
    return __builtin_bit_cast(__bf16, (unsigned short)r);
}
DEV float b2f(__bf16 x) {
    unsigned short s = __builtin_bit_cast(unsigned short, x);
    unsigned u = ((unsigned)s) << 16;
    return __builtin_bit_cast(float, u);
}
DEV unsigned cvt_pk_bf16(float a, float b) {
    unsigned r;
    asm("v_cvt_pk_bf16_f32 %0, %1, %2" : "=v"(r) : "v"(a), "v"(b));
    return r;
}
DEV void gload_lds16(const void* g, void* l) {
    __builtin_amdgcn_global_load_lds(
        (const __attribute__((address_space(1))) unsigned int*)g,
        (__attribute__((address_space(3))) unsigned int*)l,
        16, 0, 0);
}
// BK=64 swizzled LDS read: tile row-major [row][64 bf16] (128B rows), col-unit cu in [0,8)
DEV bf16x8 ldswz(const __bf16* base, int row, int cu) {
    const char* p = (const char*)base + row * 128 + (((cu) ^ (row & 7)) << 4);
    return *(const bf16x8*)p;
}

// ======= unified prep: z<5 -> weight transpose-convert; z==5 -> hs cvt + col partials ==
__global__ void k_prep(const float* __restrict__ s0, const float* __restrict__ s1,
                       const float* __restrict__ s2, const float* __restrict__ s3,
                       const float* __restrict__ s4,
                       __bf16* __restrict__ d0, __bf16* __restrict__ d1,
                       __bf16* __restrict__ d2, __bf16* __restrict__ d3,
                       __bf16* __restrict__ d4, __bf16* __restrict__ wqb,
                       const float* __restrict__ hs, __bf16* __restrict__ hsb,
                       float* __restrict__ part0) {
    const int tid = threadIdx.x;
    if (blockIdx.z == 5) {
        int idx = blockIdx.y * 32 + blockIdx.x;
        if (idx >= 512) return;
        int sc = idx >> 2, b = idx & 3;
        int c0 = tid * 4;
        float4 s = {0.f, 0.f, 0.f, 0.f};
#pragma unroll
        for (int r = 0; r < 8; r++) {
            size_t row = (size_t)b * 1024 + sc * 8 + r;
            float4 v = *(const float4*)&hs[row * 1024 + c0];
            s.x += v.x; s.y += v.y; s.z += v.z; s.w += v.w;
            bf16x4 o = { f2b(v.x), f2b(v.y), f2b(v.z), f2b(v.w) };
            *(bf16x4*)&hsb[row * 1024 + c0] = o;
        }
        *(float4*)&part0[(size_t)(sc * 4 + b) * 1024 + c0] = s;
        return;
    }
    __shared__ float t[32][33];
    const float* in; __bf16* out;
    switch (blockIdx.z) {
        case 0: in = s0; out = d0; break;
        case 1: in = s1; out = d1; break;
        case 2: in = s2; out = d2; break;
        case 3: in = s3; out = d3; break;
        default: in = s4; out = d4; break;
    }
    int tx = tid & 31, ty = tid >> 5;
    int c0 = blockIdx.x * 32, r0 = blockIdx.y * 32;
    for (int j = 0; j < 4; j++) {
        float v = in[(size_t)(r0 + ty + j * 8) * 1024 + c0 + tx];
        t[ty + j * 8][tx] = v;
        if (blockIdx.z == 0)
            wqb[(size_t)(r0 + ty + j * 8) * 1024 + c0 + tx] = f2b(v);
    }
    __syncthreads();
    for (int j = 0; j < 4; j++)
        out[(size_t)(c0 + ty + j * 8) * 1024 + r0 + tx] = f2b(t[tx][ty + j * 8]);
}

// ------- generic GEMM, BK=64, dbuf min-2-phase pipeline, swizzled LDS (R8 proven) -----
template <int EPI, int BM>
__global__ __launch_bounds__(256) void k_gemm(
    const __bf16* __restrict__ A, const __bf16* __restrict__ Bt,
    const float* __restrict__ bias, void* __restrict__ Cout, int N, int K)
{
    constexpr int MF = BM / 32;
    constexpr int ACH = BM / 32;
    __shared__ __bf16 Al[2][BM * 64];
    __shared__ __bf16 Bl[2][128 * 64];
    const int bm = blockIdx.x, bn = blockIdx.y;
    const int tid = threadIdx.x, lane = tid & 63, wid = tid >> 6;
    const int l15 = lane & 15, lg = lane >> 4;
    const int qr = (wid >> 1) * (BM / 2), qc = (wid & 1) * 64;
    f32x4 acc[MF][4] = {};

    const __bf16* Ab = A + (size_t)bm * BM * K;
    const __bf16* Bb = Bt + (size_t)bn * 128 * K;

#pragma unroll
    for (int c = 0; c < ACH; c++) {
        int ch = c * 256 + tid, row = ch >> 3, cu = (ch & 7) ^ (row & 7);
        gload_lds16(&Ab[(size_t)row * K + cu * 8], &Al[0][ch * 8]);
    }
#pragma unroll
    for (int c = 0; c < 4; c++) {
        int ch = c * 256 + tid, row = ch >> 3, cu = (ch & 7) ^ (row & 7);
        gload_lds16(&Bb[(size_t)row * K + cu * 8], &Bl[0][ch * 8]);
    }
    asm volatile("s_waitcnt vmcnt(0)" ::: "memory");
    __builtin_amdgcn_s_barrier();

    int buf = 0;
    for (int t = 0; t < K / 64; t++) {
        if (t + 1 < K / 64) {
            int k0 = (t + 1) * 64;
#pragma unroll
            for (int c = 0; c < ACH; c++) {
                int ch = c * 256 + tid, row = ch >> 3, cu = (ch & 7) ^ (row & 7);
                gload_lds16(&Ab[(size_t)row * K + k0 + cu * 8], &Al[buf ^ 1][ch * 8]);
            }
#pragma unroll
            for (int c = 0; c < 4; c++) {
                int ch = c * 256 + tid, row = ch >> 3, cu = (ch & 7) ^ (row & 7);
                gload_lds16(&Bb[(size_t)row * K + k0 + cu * 8], &Bl[buf ^ 1][ch * 8]);
            }
        }
        bf16x8 af[MF][2], bfv[4][2];
#pragma unroll
        for (int m = 0; m < MF; m++)
#pragma unroll
            for (int ks = 0; ks < 2; ks++) af[m][ks] = ldswz(&Al[buf][0], qr + m * 16 + l15, ks * 4 + lg);
#pragma unroll
        for (int n = 0; n < 4; n++)
#pragma unroll
            for (int ks = 0; ks < 2; ks++) bfv[n][ks] = ldswz(&Bl[buf][0], qc + n * 16 + l15, ks * 4 + lg);
#pragma unroll
        for (int m = 0; m < MF; m++)
#pragma unroll
            for (int n = 0; n < 4; n++) {
                acc[m][n] = __builtin_amdgcn_mfma_f32_16x16x32_bf16(af[m][0], bfv[n][0], acc[m][n], 0, 0, 0);
                acc[m][n] = __builtin_amdgcn_mfma_f32_16x16x32_bf16(af[m][1], bfv[n][1], acc[m][n], 0, 0, 0);
            }
        asm volatile("s_waitcnt vmcnt(0)" ::: "memory");
        __builtin_amdgcn_s_barrier();
        buf ^= 1;
    }
#pragma unroll
    for (int m = 0; m < MF; m++) {
        int row_base = bm * BM + qr + m * 16 + lg * 4;
#pragma unroll
        for (int n = 0; n < 4; n++) {
            int col = bn * 128 + qc + n * 16 + l15;
            float bsum = bias ? bias[col] : 0.0f;
#pragma unroll
            for (int r = 0; r < 4; r++) {
                int row = row_base + r;
                float v = acc[m][n][r] + bsum;
                if constexpr (EPI == 2) ((float*)Cout)[(size_t)row * N + col] = v;
                else ((__bf16*)Cout)[(size_t)row * N + col] = f2b(v);
            }
        }
    }
}

// ======= fused QKV+C GEMM, 128x128, BK=64 dbuf, fused P/Z + fused V-transpose (R8) ====
__global__ __launch_bounds__(256) void k_qkvc(
    const __bf16* __restrict__ A, const __bf16* __restrict__ BtAll,
    const float* __restrict__ bq, const float* __restrict__ bk, const float* __restrict__ bv,
    const float* __restrict__ gt2, const float* __restrict__ up, const float* __restrict__ uz,
    __bf16* __restrict__ mq, __bf16* __restrict__ mk_, __bf16* __restrict__ vt,
    float* __restrict__ Pf, float* __restrict__ Zf)
{
    constexpr int K = 1024;
    __shared__ __bf16 Al[2][128 * 64];
    __shared__ __bf16 Bl[2][128 * 64];
    const int bm = blockIdx.x, bn = blockIdx.y;
    const int tid = threadIdx.x, lane = tid & 63, wid = tid >> 6;
    const int l15 = lane & 15, lg = lane >> 4;
    const int qr = (wid >> 1) * 64, qc = (wid & 1) * 64;
    f32x4 acc[4][4] = {};

    const __bf16* Ab = A + (size_t)bm * 128 * K;
    const __bf16* Bb = BtAll + (size_t)bn * 128 * K;

#pragma unroll
    for (int c = 0; c < 4; c++) {
        int ch = c * 256 + tid, row = ch >> 3, cu = (ch & 7) ^ (row & 7);
        gload_lds16(&Ab[(size_t)row * K + cu * 8], &Al[0][ch * 8]);
        gload_lds16(&Bb[(size_t)row * K + cu * 8], &Bl[0][ch * 8]);
    }
    asm volatile("s_waitcnt vmcnt(0)" ::: "memory");
    __builtin_amdgcn_s_barrier();

    int buf = 0;
    for (int t = 0; t < 16; t++) {
        if (t < 15) {
            int k0 = (t + 1) * 64;
#pragma unroll
            for (int c = 0; c < 4; c++) {
                int ch = c * 256 + tid, row = ch >> 3, cu = (ch & 7) ^ (row & 7);
                gload_lds16(&Ab[(size_t)row * K + k0 + cu * 8], &Al[buf ^ 1][ch * 8]);
                gload_lds16(&Bb[(size_t)row * K + k0 + cu * 8], &Bl[buf ^ 1][ch * 8]);
            }
        }
        bf16x8 af[4][2], bfv[4][2];
#pragma unroll
        for (int m = 0; m < 4; m++)
#pragma unroll
            for (int ks = 0; ks < 2; ks++) af[m][ks] = ldswz(&Al[buf][0], qr + m * 16 + l15, ks * 4 + lg);
#pragma unroll
        for (int n = 0; n < 4; n++)
#pragma unroll
            for (int ks = 0; ks < 2; ks++) bfv[n][ks] = ldswz(&Bl[buf][0], qc + n * 16 + l15, ks * 4 + lg);
#pragma unroll
        for (int m = 0; m < 4; m++)
#pragma unroll
            for (int n = 0; n < 4; n++) {
                acc[m][n] = __builtin_amdgcn_mfma_f32_16x16x32_bf16(af[m][0], bfv[n][0], acc[m][n], 0, 0, 0);
                acc[m][n] = __builtin_amdgcn_mfma_f32_16x16x32_bf16(af[m][1], bfv[n][1], acc[m][n], 0, 0, 0);
            }
        asm volatile("s_waitcnt vmcnt(0)" ::: "memory");
        __builtin_amdgcn_s_barrier();
        buf ^= 1;
    }

    const int chunk = bn >> 3;
    if (chunk == 3) {
        const int h = (bn & 7) * 2 + (qc >> 6);
        float upv[4], uzv[4];
#pragma unroll
        for (int n = 0; n < 4; n++) {
            upv[n] = up[h * 64 + n * 16 + l15];
            uzv[n] = uz[h * 64 + n * 16 + l15];
        }
#pragma unroll
        for (int m = 0; m < 4; m++) {
            int row_base = bm * 128 + qr + m * 16 + lg * 4;
#pragma unroll
            for (int r = 0; r < 4; r++) {
                int row = row_base + r;
                float p = 0.f, z = 0.f;
#pragma unroll
                for (int n = 0; n < 4; n++) {
                    int col = (bn & 7) * 128 + qc + n * 16 + l15;
                    float cv = tanhf(acc[m][n][r] + gt2[(row >> 10) * 1024 + col]);
                    p += cv * upv[n];
                    z += cv * uzv[n];
                }
#pragma unroll
                for (int d = 1; d < 16; d <<= 1) {
                    p += __shfl_xor(p, d, 16);
                    z += __shfl_xor(z, d, 16);
                }
                if (l15 == 0) {
                    int bb = row >> 10, s = row & 1023;
                    Pf[((size_t)(bb * 16 + h)) * 1024 + s] = 1024.f / (1.f + __expf(-p));
                    Zf[((size_t)(bb * 16 + h)) * 1024 + s] = 1024.f / (1.f + __expf(-z));
                }
            }
        }
    } else if (chunk == 2) {
        const int b = bm >> 3;
#pragma unroll
        for (int m = 0; m < 4; m++) {
            int s0 = (bm & 7) * 128 + qr + m * 16 + lg * 4;
#pragma unroll
            for (int n = 0; n < 4; n++) {
                int col = (bn & 7) * 128 + qc + n * 16 + l15;
                int h = col >> 6, d = col & 63;
                float bsum = bv[col];
                bf16x4 o = { f2b(acc[m][n][0] + bsum), f2b(acc[m][n][1] + bsum),
                             f2b(acc[m][n][2] + bsum), f2b(acc[m][n][3] + bsum) };
                *(bf16x4*)&vt[((size_t)((b * 16 + h) * 64 + d)) * 1024 + s0] = o;
            }
        }
    } else {
        const float* bias = chunk == 0 ? bq : bk;
        __bf16* outp = chunk == 0 ? mq : mk_;
#pragma unroll
        for (int m = 0; m < 4; m++) {
            int row_base = bm * 128 + qr + m * 16 + lg * 4;
#pragma unroll
            for (int n = 0; n < 4; n++) {
                int col = (bn & 7) * 128 + qc + n * 16 + l15;
                float bsum = bias[col];
#pragma unroll
                for (int r = 0; r < 4; r++) {
                    int row = row_base + r;
                    outp[(size_t)row * 1024 + col] = f2b(acc[m][n][r] + bsum);
                }
            }
        }
    }
}

// ---------------- focus-path small kernels (fp32, deterministic reductions) ------------
__global__ void k_glo2(const float* __restrict__ part0, const float* __restrict__ wq,
                       float* __restrict__ glo_part) {
    __shared__ float ghs_l[256];
    int tid = threadIdx.x, kc = blockIdx.y;
    {
        int bb = tid >> 6, kk = tid & 63, k = kc * 64 + kk;
        float s = 0.f;
        for (int sc = 0; sc < 128; sc++) s += part0[(size_t)(sc * 4 + bb) * 1024 + k];
        ghs_l[tid] = s * (1.0f / 1024.f);
    }
    __syncthreads();
    int n = blockIdx.x * 256 + tid;
    float a0 = 0, a1 = 0, a2 = 0, a3 = 0;
    for (int j = 0; j < 64; j++) {
        float w = wq[(size_t)(kc * 64 + j) * 1024 + n];
        a0 += ghs_l[j] * w; a1 += ghs_l[64 + j] * w; a2 += ghs_l[128 + j] * w; a3 += ghs_l[192 + j] * w;
    }
    glo_part[(kc * 4 + 0) * 1024 + n] = a0;
    glo_part[(kc * 4 + 1) * 1024 + n] = a1;
    glo_part[(kc * 4 + 2) * 1024 + n] = a2;
    glo_part[(kc * 4 + 3) * 1024 + n] = a3;
}
__global__ void k_gt2p(const float* __restrict__ glo_part, const float* __restrict__ bq,
                       const float* __restrict__ wfg, const float* __restrict__ wfq,
                       float* __restrict__ gt_part) {
    __shared__ float glo_l[256];
    int tid = threadIdx.x, kc = blockIdx.y;
    {
        int bb = tid >> 6, kk = tid & 63, k = kc * 64 + kk;
        float s = bq[k];
        for (int k2 = 0; k2 < 16; k2++) s += glo_part[(k2 * 4 + bb) * 1024 + k];
        glo_l[tid] = s;
    }
    __syncthreads();
    int n = blockIdx.x * 256 + tid;
    float a0 = 0, a1 = 0, a2 = 0, a3 = 0, t = 0;
    for (int j = 0; j < 64; j++) {
        int k = kc * 64 + j;
        float wg = wfg[(size_t)k * 1024 + n];
        float wf = wfq[(size_t)k * 1024 + n];
        a0 += glo_l[j] * wg; a1 += glo_l[64 + j] * wg; a2 += glo_l[128 + j] * wg; a3 += glo_l[192 + j] * wg;
        t += bq[k] * wf;
    }
    gt_part[(kc * 4 + 0) * 1024 + n] = a0 + t;
    gt_part[(kc * 4 + 1) * 1024 + n] = a1 + t;
    gt_part[(kc * 4 + 2) * 1024 + n] = a2 + t;
    gt_part[(kc * 4 + 3) * 1024 + n] = a3 + t;
}
__global__ void k_red_gt(const float* __restrict__ gt_part, const float* __restrict__ bfg,
                         const float* __restrict__ bfq, float* __restrict__ gt2) {
    int i = blockIdx.x * 256 + threadIdx.x;
    int b = i >> 10, n = i & 1023;
    float s = bfg[n] + bfq[n];
    for (int kc = 0; kc < 16; kc++) s += gt_part[(kc * 4 + b) * 1024 + n];
    gt2[i] = s;
}

// ---------------- flash attention, swapped-QK^T, no-max softmax, deferred l-reduce ----
DEV bf16x8 ldfrag(const __bf16* base, int row, int colbyte) {
    const char* p = (const char*)base + (size_t)row * 128 + (colbyte ^ ((row & 7) << 4));
    return *(const bf16x8*)p;
}

__global__ __launch_bounds__(256) void k_attn(
    const __bf16* __restrict__ Q, const __bf16* __restrict__ Kx, const __bf16* __restrict__ Vt_g,
    const float* __restrict__ Pf, const float* __restrict__ Zf, __bf16* __restrict__ ctx)
{
    __shared__ __bf16 Kl[2][64 * 64];
    __shared__ __bf16 Vl[2][64 * 64];
    const int qt = blockIdx.x, h = blockIdx.y, b = blockIdx.z;
    const int tid = threadIdx.x, lane = tid & 63, wid = tid >> 6;
    const int l15 = lane & 15, lg = lane >> 4;
    const int qbase = qt * 128 + wid * 32;
    const size_t qoff = ((size_t)(b * Sc)) * DMc + h * Dh;

    bf16x8 qf[2][2];
#pragma unroll
    for (int qh = 0; qh < 2; qh++)
#pragma unroll
        for (int dh = 0; dh < 2; dh++)
            qf[qh][dh] = *(const bf16x8*)&Q[qoff + (size_t)(qbase + qh * 16 + l15) * DMc + dh * 32 + lg * 8];

    float Pr[2], Ar[2];
#pragma unroll
    for (int qh = 0; qh < 2; qh++) {
        int row = qbase + qh * 16 + l15;
        float pp = Pf[((size_t)(b * 16 + h)) * 1024 + row];
        float zz = Zf[((size_t)(b * 16 + h)) * 1024 + row];
        Pr[qh] = pp; Ar[qh] = 2.0f / (zz * zz);
    }
    float l[2] = {0.f, 0.f};   // lane-local partial; cross-lane reduced once in epilogue
    f32x4 oacc[2][4] = {};

    const __bf16* Kbase = Kx + qoff;
    const __bf16* Vbase = Vt_g + ((size_t)((b * 16 + h) * 64)) * 1024;

#pragma unroll
    for (int i = 0; i < 2; i++) {
        int ch = i * 256 + tid, row = ch >> 3, off = ch & 7;
        uint4v kv = *(const uint4v*)&Kbase[(size_t)row * DMc + off * 8];
        uint4v vv = *(const uint4v*)&Vbase[(size_t)row * 1024 + off * 8];
        *(uint4v*)((char*)&Kl[0][0] + row * 128 + ((off * 16) ^ ((row & 7) << 4))) = kv;
        *(uint4v*)((char*)&Vl[0][0] + row * 128 + ((off * 16) ^ ((row & 7) << 4))) = vv;
    }
    __syncthreads();

    for (int t = 0; t < 16; t++) {
        const int buf = t & 1;
        uint4v rk[2], rv[2];
        if (t < 15) {
#pragma unroll
            for (int i = 0; i < 2; i++) {
                int ch = i * 256 + tid, row = ch >> 3, off = ch & 7;
                rk[i] = *(const uint4v*)&Kbase[(size_t)((t + 1) * 64 + row) * DMc + off * 8];
                rv[i] = *(const uint4v*)&Vbase[(size_t)row * 1024 + (t + 1) * 64 + off * 8];
            }
        }

        f32x4 st[2][4];
        __builtin_amdgcn_s_setprio(1);
#pragma unroll
        for (int c = 0; c < 4; c++) {
            bf16x8 kb0 = ldfrag(&Kl[buf][0], c * 16 + l15, lg * 16);
            bf16x8 kb1 = ldfrag(&Kl[buf][0], c * 16 + l15, 64 + lg * 16);
#pragma unroll
            for (int qh = 0; qh < 2; qh++) {
                f32x4 a = {0.f, 0.f, 0.f, 0.f};
                a = __builtin_amdgcn_mfma_f32_16x16x32_bf16(kb0, qf[qh][0], a, 0, 0, 0);
                a = __builtin_amdgcn_mfma_f32_16x16x32_bf16(kb1, qf[qh][1], a, 0, 0, 0);
                st[qh][c] = a;
            }
        }
        __builtin_amdgcn_s_setprio(0);

        // no-max softmax; l accumulation is linear so the cross-lane reduce is DEFERRED
        int pk[2][4][2];
#pragma unroll
        for (int qh = 0; qh < 2; qh++) {
            float s[16];
            float base = (float)(t * 64 + lg * 4) - Pr[qh];
#pragma unroll
            for (int c = 0; c < 4; c++)
#pragma unroll
                for (int r = 0; r < 4; r++) {
                    float dk = base + (float)(c * 16 + r);
                    s[c * 4 + r] = __expf(st[qh][c][r] * 0.125f - dk * dk * Ar[qh]);
                }
            float rs = 0.f;
#pragma unroll
            for (int i = 0; i < 16; i++) rs += s[i];
            l[qh] += rs;
#pragma unroll
            for (int c = 0; c < 4; c++) {
                pk[qh][c][0] = (int)cvt_pk_bf16(s[c * 4 + 0], s[c * 4 + 1]);
                pk[qh][c][1] = (int)cvt_pk_bf16(s[c * 4 + 2], s[c * 4 + 3]);
            }
        }

        const int a0 = (((lg & 1) << 1) * 16 + l15) * 4;
        const int a1 = a0 + 64;
        const int selhi = lg >> 1;
#pragma unroll
        for (int kh = 0; kh < 2; kh++) {
            bf16x8 vb[4];
#pragma unroll
            for (int dt = 0; dt < 4; dt++) vb[dt] = ldfrag(&Vl[buf][0], dt * 16 + l15, kh * 64 + lg * 16);
#pragma unroll
            for (int qh = 0; qh < 2; qh++) {
                int w[4];
#pragma unroll
                for (int wi = 0; wi < 4; wi++) {
                    int addr = (wi < 2) ? a0 : a1;
                    int pr = wi & 1;
                    int va = __builtin_amdgcn_ds_bpermute(addr, pk[qh][kh * 2 + 0][pr]);
                    int vb2 = __builtin_amdgcn_ds_bpermute(addr, pk[qh][kh * 2 + 1][pr]);
                    w[wi] = selhi ? vb2 : va;
                }
                i32x4 wv = {w[0], w[1], w[2], w[3]};
                bf16x8 pa = __builtin_bit_cast(bf16x8, wv);
                __builtin_amdgcn_s_setprio(1);
#pragma unroll
                for (int dt = 0; dt < 4; dt++)
                    oacc[qh][dt] = __builtin_amdgcn_mfma_f32_16x16x32_bf16(pa, vb[dt], oacc[qh][dt], 0, 0, 0);
                __builtin_amdgcn_s_setprio(0);
            }
        }

        if (t < 15) {
#pragma unroll
            for (int i = 0; i < 2; i++) {
                int ch = i * 256 + tid, row = ch >> 3, off = ch & 7;
                *(uint4v*)((char*)&Kl[buf ^ 1][0] + row * 128 + ((off * 16) ^ ((row & 7) << 4))) = rk[i];
                *(uint4v*)((char*)&Vl[buf ^ 1][0] + row * 128 + ((off * 16) ^ ((row & 7) << 4))) = rv[i];
            }
        }
        __syncthreads();
    }

    // epilogue: single cross-lane reduce of l, then normalize + store
#pragma unroll
    for (int qh = 0; qh < 2; qh++) {
        l[qh] += __shfl_xor(l[qh], 16, 64);
        l[qh] += __shfl_xor(l[qh], 32, 64);
        float lr[4];
#pragma unroll
        for (int r = 0; r < 4; r++) lr[r] = __shfl(l[qh], lg * 4 + r, 16);
#pragma unroll
        for (int dt = 0; dt < 4; dt++)
#pragma unroll
            for (int r = 0; r < 4; r++) {
                int row = qbase + qh * 16 + lg * 4 + r;
                ctx[((size_t)(b * Sc) + row) * DMc + h * Dh + dt * 16 + l15] =
                    f2b(oacc[qh][dt][r] / lr[r]);
            }
    }
}

extern "C" void kernel_launch(void* const* d_in, const int* in_sizes, int n_in,
                              void* d_out, int out_size, void* d_ws, size_t ws_size,
                              hipStream_t stream) {
    const float* hs  = (const float*)d_in[0];
    const float* wq  = (const float*)d_in[1];
    const float* bq  = (const float*)d_in[2];
    const float* wk  = (const float*)d_in[3];
    const float* bk  = (const float*)d_in[4];
    const float* wv  = (const float*)d_in[5];
    const float* bv  = (const float*)d_in[6];
    const float* wo  = (const float*)d_in[7];
    const float* bo  = (const float*)d_in[8];
    const float* wfq = (const float*)d_in[9];
    const float* bfq = (const float*)d_in[10];
    const float* wfg = (const float*)d_in[11];
    const float* bfg = (const float*)d_in[12];
    const float* up  = (const float*)d_in[13];
    const float* uz  = (const float*)d_in[14];

    char* ws = (char*)d_ws;
    const size_t MB = 1ull << 20;
    __bf16* hsb   = (__bf16*)(ws);            // 8MB (reused by ctxb after qkvc)
    __bf16* BtAll = (__bf16*)(ws + 8 * MB);   // 8MB: [wqT|wkT|wvT|wqfT] as [4096][1024]
    __bf16* wfqT  = (__bf16*)(ws + 16 * MB);  // 2MB
    __bf16* woT   = (__bf16*)(ws + 18 * MB);  // 2MB
    __bf16* mq    = (__bf16*)(ws + 20 * MB);
    __bf16* mk    = (__bf16*)(ws + 28 * MB);
    __bf16* vt    = (__bf16*)(ws + 36 * MB);
    __bf16* ctxb  = (__bf16*)(ws);
    __bf16* wqb   = (__bf16*)(ws + 55 * MB);  // 2MB: wq row-major bf16
    char* sm = ws + 52 * MB;
    float* Pf       = (float*)(sm);                   // 256KB
    float* Zf       = (float*)(sm + (256 << 10));     // 256KB
    float* glo_part = (float*)(sm + (512 << 10));     // 256KB
    float* gt_part  = (float*)(sm + (768 << 10));     // 256KB
    float* gt2      = (float*)(sm + (1024 << 10));    // 16KB
    float* part0    = (float*)(ws + 57 * MB);         // 2MB

    k_prep<<<dim3(32, 32, 6), 256, 0, stream>>>(
        wq, wk, wv, wfq, wo,
        BtAll, BtAll + 1048576, BtAll + 2097152, wfqT, woT, wqb,
        hs, hsb, part0);

    k_glo2<<<dim3(4, 16), 256, 0, stream>>>(part0, wq, glo_part);
    k_gt2p<<<dim3(4, 16), 256, 0, stream>>>(glo_part, bq, wfg, wfq, gt_part);
    k_red_gt<<<16, 256, 0, stream>>>(gt_part, bfg, bfq, gt2);

    // BtAll slice 3 <- wqf^T where wqf = wq@wfq  (A = wfqT, Bt = wq row-major)
    k_gemm<0, 32><<<dim3(32, 8), 256, 0, stream>>>(wfqT, wqb, nullptr, BtAll + 3145728, DMc, DMc);

    // fused QKV + focus-c GEMM with in-epilogue P/Z and V-transpose
    k_qkvc<<<dim3(32, 32), 256, 0, stream>>>(hsb, BtAll, bq, bk, bv, gt2, up, uz,
                                             mq, mk, vt, Pf, Zf);

    k_attn<<<dim3(8, 16, 4), 256, 0, stream>>>(mq, mk, vt, Pf, Zf, ctxb);

    k_gemm<2, 64><<<dim3(64, 8), 256, 0, stream>>>(ctxb, woT, bo, d_out, DMc, DMc);
}